// Round 4
// baseline (1616.866 us; speedup 1.0000x reference)
//
#include <hip/hip_runtime.h>

typedef _Float16 v8h __attribute__((ext_vector_type(8)));
typedef _Float16 v4h __attribute__((ext_vector_type(4)));
typedef float    v4f __attribute__((ext_vector_type(4)));

#define GK 6432      // true K / N of the big GEMM
#define GN 6432
#define GM 2048
#define KP 6528      // K padded to 102*64 for BK=64 pipeline

// ---------------------------------------------------------------------------
// Weight conversion: wl fp32 [6432,6432] -> fp16 [6432, KP], K-pad cols zeroed
// ---------------------------------------------------------------------------
__global__ void convert_w(const float* __restrict__ wl, _Float16* __restrict__ Wh)
{
    const int row = blockIdx.y;                       // 0..6431
    const int col = (blockIdx.x * 256 + threadIdx.x) * 4;
    if (col >= KP) return;
    v4h h;
    if (col < GK) {
        const float4 f = *(const float4*)(wl + (long)row * GK + col);
        h[0] = (_Float16)f.x; h[1] = (_Float16)f.y;
        h[2] = (_Float16)f.z; h[3] = (_Float16)f.w;
    } else {
        h[0] = (_Float16)0.f; h[1] = (_Float16)0.f;
        h[2] = (_Float16)0.f; h[3] = (_Float16)0.f;
    }
    *(v4h*)(Wh + (long)row * KP + col) = h;
}

// ---------------------------------------------------------------------------
// Multi-scale conv feature extractor (unchanged). F0 [2048, KP] fp16.
// ---------------------------------------------------------------------------
#define SX   0
#define SX2  2048
#define SX4  3136
#define SW1  3712
#define SB1  4032
#define SW2  4048
#define SB2  6608
#define SP1  6640
#define LDSZ 13808

__global__ __launch_bounds__(256) void conv_feat(
    const float* __restrict__ x,
    const float* __restrict__ w1, const float* __restrict__ b1,
    const float* __restrict__ w2, const float* __restrict__ b2,
    _Float16* __restrict__ F0)
{
    __shared__ float lds[LDSZ];
    const int tid = threadIdx.x;
    const long b  = blockIdx.x;

    for (int i = tid; i < 1920; i += 256) {
        int c = i / 480, t = i % 480;
        lds[SX + c * 512 + t] = x[(b * 4 + c) * 480 + t];
    }
    for (int i = tid; i < 320;  i += 256) lds[SW1 + i] = w1[i];
    for (int i = tid; i < 16;   i += 256) lds[SB1 + i] = b1[i];
    for (int i = tid; i < 2560; i += 256) lds[SW2 + i] = w2[i];
    for (int i = tid; i < 32;   i += 256) lds[SB2 + i] = b2[i];
    for (int i = tid; i < KP - GK; i += 256) F0[b * KP + GK + i] = (_Float16)0.f;
    __syncthreads();

    for (int i = tid; i < 960; i += 256) {
        int c = i / 240, t = i % 240;
        lds[SX2 + c * 272 + t] = 0.5f * (lds[SX + c * 512 + 2 * t] + lds[SX + c * 512 + 2 * t + 1]);
    }
    for (int i = tid; i < 480; i += 256) {
        int c = i / 120, t = i % 120;
        float s = lds[SX + c * 512 + 4 * t]     + lds[SX + c * 512 + 4 * t + 1]
                + lds[SX + c * 512 + 4 * t + 2] + lds[SX + c * 512 + 4 * t + 3];
        lds[SX4 + c * 144 + t] = 0.25f * s;
    }
    __syncthreads();

    for (int jid = tid; jid < 16 * 34; jid += 256) {
        const int c1 = jid / 34, rid = jid % 34;
        const int sidx = (rid < 19) ? 0 : (rid < 29 ? 1 : 2);
        const int r0   = (sidx == 0) ? rid : (sidx == 1 ? rid - 19 : rid - 29);
        const int u0   = r0 * 13;
        const int xbase  = (sidx == 0) ? SX  : (sidx == 1 ? SX2 : SX4);
        const int xpitch = (sidx == 0) ? 512 : (sidx == 1 ? 272 : 144);
        const int P      = (sidx == 0) ? 238 : (sidx == 1 ? 118 : 58);
        const int pofs   = (sidx == 0) ? 0   : (sidx == 1 ? 238 : 356);

        float acc[26];
        const float bias = lds[SB1 + c1];
        #pragma unroll
        for (int i = 0; i < 26; ++i) acc[i] = bias;

        #pragma unroll
        for (int ci = 0; ci < 4; ++ci) {
            float w[30];
            const float* xr = &lds[xbase + ci * xpitch + 2 * u0];
            #pragma unroll
            for (int q = 0; q < 15; ++q) {
                float2 t2 = *(const float2*)(xr + 2 * q);
                w[2 * q] = t2.x; w[2 * q + 1] = t2.y;
            }
            float wt[5];
            #pragma unroll
            for (int k = 0; k < 5; ++k) wt[k] = lds[SW1 + (c1 * 4 + ci) * 5 + k];
            #pragma unroll
            for (int i = 0; i < 26; ++i) {
                #pragma unroll
                for (int k = 0; k < 5; ++k) acc[i] += w[i + k] * wt[k];
            }
        }
        #pragma unroll
        for (int i = 0; i < 13; ++i) {
            int u = u0 + i;
            if (u < P)
                lds[SP1 + c1 * 448 + pofs + u] = fmaxf(fmaxf(acc[2 * i], acc[2 * i + 1]), 0.f);
        }
    }
    __syncthreads();

    for (int jid = tid; jid < 32 * 17; jid += 256) {
        const int c2 = jid / 17, rid = jid % 17;
        const int sidx = (rid < 9) ? 0 : (rid < 14 ? 1 : 2);
        const int r0   = (sidx == 0) ? rid : (sidx == 1 ? rid - 9 : rid - 14);
        const int v0   = r0 * 13;
        const int pbase = (sidx == 0) ? 0   : (sidx == 1 ? 238 : 356);
        const int Pv    = (sidx == 0) ? 117 : (sidx == 1 ? 57  : 27);
        const int vout  = (sidx == 0) ? 0   : (sidx == 1 ? 117 : 174);

        float acc[26];
        const float bias = lds[SB2 + c2];
        #pragma unroll
        for (int i = 0; i < 26; ++i) acc[i] = bias;

        for (int c1 = 0; c1 < 16; ++c1) {
            float w[30];
            const float* pr = &lds[SP1 + c1 * 448 + pbase + 2 * v0];
            #pragma unroll
            for (int q = 0; q < 15; ++q) {
                float2 t2 = *(const float2*)(pr + 2 * q);
                w[2 * q] = t2.x; w[2 * q + 1] = t2.y;
            }
            float wt[5];
            #pragma unroll
            for (int k = 0; k < 5; ++k) wt[k] = lds[SW2 + (c2 * 16 + c1) * 5 + k];
            #pragma unroll
            for (int i = 0; i < 26; ++i) {
                #pragma unroll
                for (int k = 0; k < 5; ++k) acc[i] += w[i + k] * wt[k];
            }
        }
        #pragma unroll
        for (int i = 0; i < 13; ++i) {
            int v = v0 + i;
            if (v < Pv) {
                float f = fmaxf(fmaxf(acc[2 * i], acc[2 * i + 1]), 0.f);
                F0[b * KP + c2 * 201 + vout + v] = (_Float16)f;
            }
        }
    }
}

// ---------------------------------------------------------------------------
// 256x256x(BK=64) NT GEMM, A-in-LDS / B-direct-to-registers.
// Rationale: rounds were LDS-pipe-bound (192KB reads + 64KB DMA writes per
// K-tile). B has only 2x intra-block reuse -> stream it from L2/L3 straight
// to VGPRs (16 full 64B lines per load instr). LDS now carries A only
// (128KB reads + 32KB writes per round).
// 2 phases / 4 barriers per round; 16x16x32 MFMA with R2's verified
// conflict-free swizzle + epilogue.
//
// Per-wave vmcnt ledger (all stage sets disjoint per wave; cross-wave
// visibility via the phase barriers after each wave's own drain):
//   P1 issues: h1-stage (2 GLD, tile kt+1 -> other buf) + 8 B-loads (B(kt+1))
//   P2 issues: h0-stage (2 GLD, tile kt+2 -> cur buf)
//   vmcnt(2) at P2 end keeps ONLY P2's h0 stage in flight; drains P1's
//   B(kt+1)+h1(kt+1) (needed next round) and last round's h0 (needed in 2).
// Region safety: h0' = rows {0-63,128-191} last read at P1 (proven free by
// P1's closing barrier; staged at P2). h1' = {64-127,192-255} last read at
// P2 (proven free by round-final barrier; staged at next round's P1, which
// targets the OTHER buffer than that round computes).
// ---------------------------------------------------------------------------
__global__ __launch_bounds__(512, 2) void gemm2p(
    const _Float16* __restrict__ A, const _Float16* __restrict__ Bw,
    const float* __restrict__ bias, _Float16* __restrict__ C)
{
    __shared__ _Float16 sA[2][256 * 64];    // 64 KB
    __shared__ _Float16 ldspad[10240];      // +20 KB => 84 KB: forces 1 block/CU

    const int tid  = threadIdx.x;
    const int lane = tid & 63;
    const int wave = tid >> 6;
    const int wr   = wave >> 2;          // m-half
    const int wc   = wave & 3;           // n-quarter

    // keep pad allocated (volatile store cannot be eliminated)
    *(volatile _Float16*)&ldspad[tid] = (_Float16)0.f;

    const int id = blockIdx.x;           // 208 = 8 m-tiles x 26 n-tiles
    const long tile_m = (long)(id & 7) << 8;   // m-tile = XCD id: A strip L2-resident
    const long tile_n = (long)(id >> 3) << 8;

    // ---- A staging geometry (linear LDS dst; pre-XOR-swizzled source) ----
    const int lrow  = lane >> 3;                 // 0..7
    const int lcol  = ((lane & 7) ^ lrow) << 3;  // fp16 elems
    const int base0 = wr * 128 + wc * 16;        // this wave's h0' rows [base0,+16)
    const _Float16* pA0 = A + (tile_m + base0 + lrow) * (long)KP + lcol;  // h0'
    const _Float16* pA1 = pA0 + 64L * KP;                                 // h1' (+64 rows)
    const int d00 = base0 * 64,        d01 = (base0 + 8) * 64;
    const int d10 = (base0 + 64) * 64, d11 = (base0 + 72) * 64;

#define GLD(p, d) __builtin_amdgcn_global_load_lds(                          \
        (const __attribute__((address_space(1))) void*)(p),                  \
        (__attribute__((address_space(3))) void*)(d), 16, 0, 0)

    // ---- B direct-load geometry (per-lane rows, clamped on last n-tile) ----
    const int fr = lane & 15;
    const int fp = lane >> 4;                    // k-phase 0..3
    long rS0 = tile_n + wc * 64 + wr * 32 + fr;
    long rS1 = rS0 + 16;
    long rO0 = tile_n + wc * 64 + (1 - wr) * 32 + fr;
    long rO1 = rO0 + 16;
    if (rS0 > 6431) rS0 = 6431;   // clamped rows feed only cols the epilogue
    if (rS1 > 6431) rS1 = 6431;   // discards/zeroes
    if (rO0 > 6431) rO0 = 6431;
    if (rO1 > 6431) rO1 = 6431;
    const _Float16* qS0 = Bw + rS0 * (long)KP + fp * 8;
    const _Float16* qS1 = Bw + rS1 * (long)KP + fp * 8;
    const _Float16* qO0 = Bw + rO0 * (long)KP + fp * 8;
    const _Float16* qO1 = Bw + rO1 * (long)KP + fp * 8;

    // B register sets (double-buffered across rounds, statically named)
    v8h bAS[2][2], bAO[2][2], bBS[2][2], bBO[2][2];

#define LOADB(S, O) {                                                        \
    S[0][0] = *(const v8h*)(qS0);      S[0][1] = *(const v8h*)(qS0 + 32);    \
    S[1][0] = *(const v8h*)(qS1);      S[1][1] = *(const v8h*)(qS1 + 32);    \
    O[0][0] = *(const v8h*)(qO0);      O[0][1] = *(const v8h*)(qO0 + 32);    \
    O[1][0] = *(const v8h*)(qO1);      O[1][1] = *(const v8h*)(qO1 + 32);    \
    qS0 += 64; qS1 += 64; qO0 += 64; qO1 += 64; }

    // ---- A fragment read geometry (R2-verified conflict-free swizzle) ----
    const int sw    = fr & 7;
    const int slot0 = ((fp)     ^ sw) << 3;
    const int slot1 = ((fp + 4) ^ sw) << 3;
    const int abase = (wr * 128 + fr) * 64;

    v8h af[4][2];
    v4f accS[8][2], accO[8][2];
    #pragma unroll
    for (int m = 0; m < 8; ++m) {
        #pragma unroll
        for (int ni = 0; ni < 2; ++ni) {
            v4f z = {0.f, 0.f, 0.f, 0.f};
            accS[m][ni] = z; accO[m][ni] = z;
        }
    }

#define LDA(CA, H) { _Pragma("unroll")                                       \
    for (int mi = 0; mi < 4; ++mi) {                                         \
        af[mi][0] = *(const v8h*)&(CA)[abase + (H) * 4096 + mi * 1024 + slot0]; \
        af[mi][1] = *(const v8h*)&(CA)[abase + (H) * 4096 + mi * 1024 + slot1]; \
    } }

#define MMAQ(ACC, MH, BF) { _Pragma("unroll")                                \
    for (int mi = 0; mi < 4; ++mi) { _Pragma("unroll")                       \
        for (int ni = 0; ni < 2; ++ni) {                                     \
            ACC[(MH)*4+mi][ni] = __builtin_amdgcn_mfma_f32_16x16x32_f16(     \
                af[mi][0], BF[ni][0], ACC[(MH)*4+mi][ni], 0, 0, 0);          \
            ACC[(MH)*4+mi][ni] = __builtin_amdgcn_mfma_f32_16x16x32_f16(     \
                af[mi][1], BF[ni][1], ACC[(MH)*4+mi][ni], 0, 0, 0);          \
        } } }

    // qA0: h0-stage src (tile kt+2); qA1: h1-stage src (tile kt+1)
    const _Float16* qA0 = pA0 + 128;
    const _Float16* qA1 = pA1 + 64;

#define ROUND(CB, BCS, BCO, BNS, BNO, S1, S0, VN) {                          \
    /* P1: read A-h0; stage h1(kt+1)->other buf; load B(kt+1); MFMA mh0 */   \
    LDA(sA[CB], 0);                                                          \
    if (S1) { GLD(qA1, &sA[(CB)^1][d10]); GLD(qA1 + 8L*KP, &sA[(CB)^1][d11]); } \
    if (S1) LOADB(BNS, BNO);                                                 \
    __builtin_amdgcn_s_barrier();                                            \
    asm volatile("s_waitcnt lgkmcnt(0)" ::: "memory");                       \
    __builtin_amdgcn_s_setprio(1);                                           \
    MMAQ(accS, 0, BCS); MMAQ(accO, 0, BCO);                                  \
    __builtin_amdgcn_s_setprio(0);                                           \
    __builtin_amdgcn_s_barrier();                                            \
    /* P2: stage h0(kt+2)->cur buf; read A-h1; MFMA mh1; counted vmcnt */    \
    if (S0) { GLD(qA0, &sA[CB][d00]); GLD(qA0 + 8L*KP, &sA[CB][d01]); }      \
    LDA(sA[CB], 1);                                                          \
    __builtin_amdgcn_s_barrier();                                            \
    asm volatile("s_waitcnt lgkmcnt(0)" ::: "memory");                       \
    __builtin_amdgcn_s_setprio(1);                                           \
    MMAQ(accS, 1, BCS); MMAQ(accO, 1, BCO);                                  \
    __builtin_amdgcn_s_setprio(0);                                           \
    asm volatile("s_waitcnt vmcnt(" #VN ")" ::: "memory");                   \
    __builtin_amdgcn_s_barrier();                                            \
    qA0 += 64; qA1 += 64; }

    // ---- prologue: t0 full -> buf0; B(0) -> bA; t1 h0' -> buf1 ----
    GLD(pA0, &sA[0][d00]); GLD(pA0 + 8L * KP, &sA[0][d01]);
    GLD(pA1, &sA[0][d10]); GLD(pA1 + 8L * KP, &sA[0][d11]);
    LOADB(bAS, bAO);                       // B(0); q* advance to k=64
    GLD(pA0 + 64, &sA[1][d00]); GLD(pA0 + 64 + 8L * KP, &sA[1][d01]);
    asm volatile("s_waitcnt vmcnt(0)" ::: "memory");
    __builtin_amdgcn_s_barrier();

    // ---- main loop: kt pairs (0,1)...(98,99), then peeled (100,101) ----
    for (int kt = 0; kt < 100; kt += 2) {
        ROUND(0, bAS, bAO, bBS, bBO, 1, 1, 2);
        ROUND(1, bBS, bBO, bAS, bAO, 1, 1, 2);
    }
    ROUND(0, bAS, bAO, bBS, bBO, 1, 0, 0);   // kt=100: stage h1(t101)+B(101), no h0
    ROUND(1, bBS, bBO, bAS, bAO, 0, 0, 0);   // kt=101: compute only

    // ---- epilogue: C/D layout col=lane&15, row=(lane>>4)*4+reg ----
#define EPI(ACC, COL0) { _Pragma("unroll")                                   \
    for (int ni = 0; ni < 2; ++ni) {                                         \
        const long col = (COL0) + ni * 16;                                   \
        if (col < KP) {                                                      \
            const bool val = col < GN;                                       \
            const float bv = val ? bias[col] : 0.f;                          \
            _Pragma("unroll")                                                \
            for (int m = 0; m < 8; ++m) {                                    \
                const long row = tile_m + wr * 128 + m * 16 + fp * 4;        \
                _Pragma("unroll")                                            \
                for (int r = 0; r < 4; ++r) {                                \
                    float v = ACC[m][ni][r] + bv;                            \
                    v = v > 0.f ? v : 0.f;                                   \
                    C[(row + r) * (long)KP + col] = val ? (_Float16)v        \
                                                        : (_Float16)0.f;     \
                }                                                            \
            }                                                                \
        }                                                                    \
    } }

    const long colS0 = tile_n + wc * 64 + wr * 32 + fr;
    const long colO0 = tile_n + wc * 64 + (1 - wr) * 32 + fr;
    EPI(accS, colS0);
    EPI(accO, colO0);

#undef GLD
#undef LOADB
#undef LDA
#undef MMAQ
#undef ROUND
#undef EPI
}

// ---------------------------------------------------------------------------
// Final projection: out[b,o] = sum_k F[b,k]*wo[o,k] + bo[o].
// ---------------------------------------------------------------------------
__global__ __launch_bounds__(256) void final_out(
    const _Float16* __restrict__ F, const float* __restrict__ wo,
    const float* __restrict__ bo, float* __restrict__ out)
{
    __shared__ float red[4][8];
    const long b   = blockIdx.x;
    const int tid  = threadIdx.x;
    const int lane = tid & 63;
    const int wave = tid >> 6;
    float acc[5] = {0.f, 0.f, 0.f, 0.f, 0.f};
    const _Float16* f = F + b * KP;

    const int c1 = (wave + 1) * 402;
    for (int c = wave * 402 + lane; c < c1; c += 64) {
        const int k = c << 2;
        v4h f4 = *(const v4h*)(f + k);
        const float f0 = (float)f4[0], f1 = (float)f4[1];
        const float f2 = (float)f4[2], f3 = (float)f4[3];
        #pragma unroll
        for (int o = 0; o < 5; ++o) {
            const float4 w4 = *(const float4*)(wo + o * GK + k);
            acc[o] += f0 * w4.x + f1 * w4.y + f2 * w4.z + f3 * w4.w;
        }
    }
    #pragma unroll
    for (int o = 0; o < 5; ++o) {
        #pragma unroll
        for (int off = 32; off > 0; off >>= 1) acc[o] += __shfl_down(acc[o], off, 64);
    }
    if (lane == 0) {
        #pragma unroll
        for (int o = 0; o < 5; ++o) red[wave][o] = acc[o];
    }
    __syncthreads();
    if (tid < 5)
        out[b * 5 + tid] = red[0][tid] + red[1][tid] + red[2][tid] + red[3][tid] + bo[tid];
}

// ---------------------------------------------------------------------------
extern "C" void kernel_launch(void* const* d_in, const int* in_sizes, int n_in,
                              void* d_out, int out_size, void* d_ws, size_t ws_size,
                              hipStream_t stream)
{
    const float* x  = (const float*)d_in[0];
    const float* w1 = (const float*)d_in[1];
    const float* b1 = (const float*)d_in[2];
    const float* w2 = (const float*)d_in[3];
    const float* b2 = (const float*)d_in[4];
    const float* wl = (const float*)d_in[5];
    const float* bl = (const float*)d_in[6];
    const float* wo = (const float*)d_in[7];
    const float* bo = (const float*)d_in[8];
    float* out = (float*)d_out;

    char* ws = (char*)d_ws;
    _Float16* Wh = (_Float16*)ws;                                   // 6432*6528*2 = 83,976,192 B
    _Float16* F0 = (_Float16*)(ws + 83976192);                      // 2048*6528*2 = 26,738,688 B
    _Float16* F1 = (_Float16*)(ws + 83976192 + 26738688);

    convert_w<<<dim3(7, GN), 256, 0, stream>>>(wl, Wh);
    conv_feat<<<GM, 256, 0, stream>>>(x, w1, b1, w2, b2, F0);
    gemm2p<<<208, 512, 0, stream>>>(F0, Wh, bl, F1);
    gemm2p<<<208, 512, 0, stream>>>(F1, Wh, bl, F0);
    gemm2p<<<208, 512, 0, stream>>>(F0, Wh, bl, F1);
    gemm2p<<<208, 512, 0, stream>>>(F1, Wh, bl, F0);
    final_out<<<GM, 256, 0, stream>>>(F0, wo, bo, out);
}

// Round 5
// 1178.934 us; speedup vs baseline: 1.3715x; 1.3715x over previous
//
#include <hip/hip_runtime.h>

typedef _Float16 v8h __attribute__((ext_vector_type(8)));
typedef _Float16 v4h __attribute__((ext_vector_type(4)));
typedef float    v4f __attribute__((ext_vector_type(4)));

#define GK 6432      // true K / N of the big GEMM
#define GN 6432
#define GM 2048
#define KP 6528      // K padded to 102*64 for BK=64 pipeline

// ---------------------------------------------------------------------------
// Weight conversion: wl fp32 [6432,6432] -> fp16 [6432, KP], K-pad cols zeroed
// ---------------------------------------------------------------------------
__global__ void convert_w(const float* __restrict__ wl, _Float16* __restrict__ Wh)
{
    const int row = blockIdx.y;                       // 0..6431
    const int col = (blockIdx.x * 256 + threadIdx.x) * 4;
    if (col >= KP) return;
    v4h h;
    if (col < GK) {
        const float4 f = *(const float4*)(wl + (long)row * GK + col);
        h[0] = (_Float16)f.x; h[1] = (_Float16)f.y;
        h[2] = (_Float16)f.z; h[3] = (_Float16)f.w;
    } else {
        h[0] = (_Float16)0.f; h[1] = (_Float16)0.f;
        h[2] = (_Float16)0.f; h[3] = (_Float16)0.f;
    }
    *(v4h*)(Wh + (long)row * KP + col) = h;
}

// ---------------------------------------------------------------------------
// Multi-scale conv feature extractor (unchanged). F0 [2048, KP] fp16.
// ---------------------------------------------------------------------------
#define SX   0
#define SX2  2048
#define SX4  3136
#define SW1  3712
#define SB1  4032
#define SW2  4048
#define SB2  6608
#define SP1  6640
#define LDSZ 13808

__global__ __launch_bounds__(256) void conv_feat(
    const float* __restrict__ x,
    const float* __restrict__ w1, const float* __restrict__ b1,
    const float* __restrict__ w2, const float* __restrict__ b2,
    _Float16* __restrict__ F0)
{
    __shared__ float lds[LDSZ];
    const int tid = threadIdx.x;
    const long b  = blockIdx.x;

    for (int i = tid; i < 1920; i += 256) {
        int c = i / 480, t = i % 480;
        lds[SX + c * 512 + t] = x[(b * 4 + c) * 480 + t];
    }
    for (int i = tid; i < 320;  i += 256) lds[SW1 + i] = w1[i];
    for (int i = tid; i < 16;   i += 256) lds[SB1 + i] = b1[i];
    for (int i = tid; i < 2560; i += 256) lds[SW2 + i] = w2[i];
    for (int i = tid; i < 32;   i += 256) lds[SB2 + i] = b2[i];
    for (int i = tid; i < KP - GK; i += 256) F0[b * KP + GK + i] = (_Float16)0.f;
    __syncthreads();

    for (int i = tid; i < 960; i += 256) {
        int c = i / 240, t = i % 240;
        lds[SX2 + c * 272 + t] = 0.5f * (lds[SX + c * 512 + 2 * t] + lds[SX + c * 512 + 2 * t + 1]);
    }
    for (int i = tid; i < 480; i += 256) {
        int c = i / 120, t = i % 120;
        float s = lds[SX + c * 512 + 4 * t]     + lds[SX + c * 512 + 4 * t + 1]
                + lds[SX + c * 512 + 4 * t + 2] + lds[SX + c * 512 + 4 * t + 3];
        lds[SX4 + c * 144 + t] = 0.25f * s;
    }
    __syncthreads();

    for (int jid = tid; jid < 16 * 34; jid += 256) {
        const int c1 = jid / 34, rid = jid % 34;
        const int sidx = (rid < 19) ? 0 : (rid < 29 ? 1 : 2);
        const int r0   = (sidx == 0) ? rid : (sidx == 1 ? rid - 19 : rid - 29);
        const int u0   = r0 * 13;
        const int xbase  = (sidx == 0) ? SX  : (sidx == 1 ? SX2 : SX4);
        const int xpitch = (sidx == 0) ? 512 : (sidx == 1 ? 272 : 144);
        const int P      = (sidx == 0) ? 238 : (sidx == 1 ? 118 : 58);
        const int pofs   = (sidx == 0) ? 0   : (sidx == 1 ? 238 : 356);

        float acc[26];
        const float bias = lds[SB1 + c1];
        #pragma unroll
        for (int i = 0; i < 26; ++i) acc[i] = bias;

        #pragma unroll
        for (int ci = 0; ci < 4; ++ci) {
            float w[30];
            const float* xr = &lds[xbase + ci * xpitch + 2 * u0];
            #pragma unroll
            for (int q = 0; q < 15; ++q) {
                float2 t2 = *(const float2*)(xr + 2 * q);
                w[2 * q] = t2.x; w[2 * q + 1] = t2.y;
            }
            float wt[5];
            #pragma unroll
            for (int k = 0; k < 5; ++k) wt[k] = lds[SW1 + (c1 * 4 + ci) * 5 + k];
            #pragma unroll
            for (int i = 0; i < 26; ++i) {
                #pragma unroll
                for (int k = 0; k < 5; ++k) acc[i] += w[i + k] * wt[k];
            }
        }
        #pragma unroll
        for (int i = 0; i < 13; ++i) {
            int u = u0 + i;
            if (u < P)
                lds[SP1 + c1 * 448 + pofs + u] = fmaxf(fmaxf(acc[2 * i], acc[2 * i + 1]), 0.f);
        }
    }
    __syncthreads();

    for (int jid = tid; jid < 32 * 17; jid += 256) {
        const int c2 = jid / 17, rid = jid % 17;
        const int sidx = (rid < 9) ? 0 : (rid < 14 ? 1 : 2);
        const int r0   = (sidx == 0) ? rid : (sidx == 1 ? rid - 9 : rid - 14);
        const int v0   = r0 * 13;
        const int pbase = (sidx == 0) ? 0   : (sidx == 1 ? 238 : 356);
        const int Pv    = (sidx == 0) ? 117 : (sidx == 1 ? 57  : 27);
        const int vout  = (sidx == 0) ? 0   : (sidx == 1 ? 117 : 174);

        float acc[26];
        const float bias = lds[SB2 + c2];
        #pragma unroll
        for (int i = 0; i < 26; ++i) acc[i] = bias;

        for (int c1 = 0; c1 < 16; ++c1) {
            float w[30];
            const float* pr = &lds[SP1 + c1 * 448 + pbase + 2 * v0];
            #pragma unroll
            for (int q = 0; q < 15; ++q) {
                float2 t2 = *(const float2*)(pr + 2 * q);
                w[2 * q] = t2.x; w[2 * q + 1] = t2.y;
            }
            float wt[5];
            #pragma unroll
            for (int k = 0; k < 5; ++k) wt[k] = lds[SW2 + (c2 * 16 + c1) * 5 + k];
            #pragma unroll
            for (int i = 0; i < 26; ++i) {
                #pragma unroll
                for (int k = 0; k < 5; ++k) acc[i] += w[i + k] * wt[k];
            }
        }
        #pragma unroll
        for (int i = 0; i < 13; ++i) {
            int v = v0 + i;
            if (v < Pv) {
                float f = fmaxf(fmaxf(acc[2 * i], acc[2 * i + 1]), 0.f);
                F0[b * KP + c2 * 201 + vout + v] = (_Float16)f;
            }
        }
    }
}

// ---------------------------------------------------------------------------
// 256x256x(BK=64) NT GEMM, 16 waves (1024 threads, 4 waves/SIMD).
// Attacks the measured overlap bound: MFMA-busy/round is invariant ~1700cy
// across R2/R3/R4 while round=5080cy at 2 waves/SIMD lockstep. 4 waves/SIMD
// gives cross-wave skew inside each barrier phase -> ds_read and MFMA of
// different waves overlap.
// Waves (wm,wn) in 4x4 grid; per-wave output 64x64 (acc = 16 frags = 64 f32,
// fits 128-unified-VGPR/wave cap: 64 AGPR + ~56 arch).
// 4 phases per K-tile: af[4][2] loaded once at P1 (8 ds_reads), one bf
// n-frag (2 reads) + 8 MFMA per phase.
// Staging (per-wave symmetric, 4 GLD/thread/K-tile, R2-verified swizzle):
//   P1: B(kt+1) stripes{2,3} -> buf^1 (1 GLD)  [region: read at prev-tile
//       P3/P4 from buf^1, freed by prev round-final barrier]
//   P2: A(kt+2)              -> buf   (2 GLD)  [A read only at P1; freed by
//       P1's closing barrier]
//   P3: B(kt+2) stripes{0,1} -> buf   (1 GLD)  [stripe p read at phase p;
//       freed by P2's closing barrier]
// vmcnt(3) once per round = {P2(2) + P3(1)} stay in flight; each GLD gets
// >=3 phases issue->drain slack. Tail: kt=100 vmcnt(0); kt=101 no stages.
// ---------------------------------------------------------------------------
__global__ __launch_bounds__(1024, 4) void gemm16(
    const _Float16* __restrict__ A, const _Float16* __restrict__ Bw,
    const float* __restrict__ bias, _Float16* __restrict__ C)
{
    __shared__ _Float16 sA[2][256 * 64];   // 64 KB
    __shared__ _Float16 sB[2][256 * 64];   // total 128 KB

    const int tid  = threadIdx.x;
    const int lane = tid & 63;
    const int wave = tid >> 6;           // 0..15
    const int wm   = wave >> 2;          // m quarter (0..3)
    const int wn   = wave & 3;           // n quarter (0..3)

    const int id = blockIdx.x;           // 208 = 8 m-tiles x 26 n-tiles
    const long tile_m = (long)(id & 7) << 8;   // m-tile = XCD id: A strip L2-resident
    const long tile_n = (long)(id >> 3) << 8;

    // ---- staging geometry (linear LDS dst; pre-XOR-swizzled source) ----
    const int lrow = lane >> 3;                  // 0..7
    const int lcol = ((lane & 7) ^ lrow) << 3;   // fp16 elems

    // A: wave stages rows [wave*16, +16) (2 GLD)
    const _Float16* pAst = A + (tile_m + wave * 16 + lrow) * (long)KP + lcol;
    const int dA0 = wave * 16 * 64, dA1 = dA0 + 512;

    // B: stripes01 rows [(w>>2)*64 + (w&3)*8, +8); stripes23 = +32 (1 GLD each)
    const int bRow01 = (wave >> 2) * 64 + (wave & 3) * 8;
    long rb01 = tile_n + bRow01;         // +lrow per lane below
    long rb23 = rb01 + 32;
    long r01l = rb01 + lrow; if (r01l > 6431) r01l = 6431;  // last-n-tile clamp:
    long r23l = rb23 + lrow; if (r23l > 6431) r23l = 6431;  // garbage cols discarded
    const _Float16* pB01 = Bw + r01l * (long)KP + lcol;
    const _Float16* pB23 = Bw + r23l * (long)KP + lcol;
    const int dB01 = bRow01 * 64;
    const int dB23 = dB01 + 32 * 64;

#define GLD(p, d) __builtin_amdgcn_global_load_lds(                          \
        (const __attribute__((address_space(1))) void*)(p),                  \
        (__attribute__((address_space(3))) void*)(d), 16, 0, 0)

#define STAGE_A(CUR, q)   { GLD(q, &sA[CUR][dA0]); GLD((q) + 8L * KP, &sA[CUR][dA1]); }
#define STAGE_B01(CUR, q) { GLD(q, &sB[CUR][dB01]); }
#define STAGE_B23(CUR, q) { GLD(q, &sB[CUR][dB23]); }

    // ---- fragment read geometry (R2-verified conflict-free swizzle) ----
    const int fr = lane & 15;
    const int fp = lane >> 4;                    // k-phase 0..3
    const int sw = fr & 7;
    const int slot0 = ((fp)     ^ sw) << 3;
    const int slot1 = ((fp + 4) ^ sw) << 3;
    const int arow0 = wm * 64 + fr;              // af row for mi=0
    const int brow0 = wn * 64 + fr;              // bf row for p=0

    v8h af[4][2], bf0, bf1;
    v4f acc[4][4];
    #pragma unroll
    for (int mi = 0; mi < 4; ++mi) {
        #pragma unroll
        for (int nf = 0; nf < 4; ++nf) { v4f z = {0.f, 0.f, 0.f, 0.f}; acc[mi][nf] = z; }
    }

#define LDAALL(CUR) { _Pragma("unroll")                                      \
    for (int mi = 0; mi < 4; ++mi) {                                         \
        af[mi][0] = *(const v8h*)&sA[CUR][(arow0 + mi * 16) * 64 + slot0];   \
        af[mi][1] = *(const v8h*)&sA[CUR][(arow0 + mi * 16) * 64 + slot1];   \
    } }

#define LDB(CUR, P) {                                                        \
    bf0 = *(const v8h*)&sB[CUR][(brow0 + (P) * 16) * 64 + slot0];            \
    bf1 = *(const v8h*)&sB[CUR][(brow0 + (P) * 16) * 64 + slot1]; }

#define MMAP(P) { _Pragma("unroll")                                          \
    for (int mi = 0; mi < 4; ++mi) {                                         \
        acc[mi][P] = __builtin_amdgcn_mfma_f32_16x16x32_f16(af[mi][0], bf0,  \
                                                            acc[mi][P], 0, 0, 0); \
        acc[mi][P] = __builtin_amdgcn_mfma_f32_16x16x32_f16(af[mi][1], bf1,  \
                                                            acc[mi][P], 0, 0, 0); \
    } }

#define ROUND(CUR, S1, S2, VN) {                                             \
    /* P1: af(all) + bf(0); stage B(kt+1)s23 -> buf^1; MFMA nf=0 */          \
    LDAALL(CUR); LDB(CUR, 0);                                                \
    if (S1) STAGE_B23((CUR) ^ 1, qB23);                                      \
    __builtin_amdgcn_s_barrier();                                            \
    asm volatile("s_waitcnt lgkmcnt(0)" ::: "memory");                       \
    __builtin_amdgcn_s_setprio(1);                                           \
    MMAP(0);                                                                 \
    __builtin_amdgcn_s_setprio(0);                                           \
    __builtin_amdgcn_s_barrier();                                            \
    /* P2: bf(1); stage A(kt+2) -> buf; MFMA nf=1 */                         \
    LDB(CUR, 1);                                                             \
    if (S2) STAGE_A(CUR, qA);                                                \
    __builtin_amdgcn_s_barrier();                                            \
    asm volatile("s_waitcnt lgkmcnt(0)" ::: "memory");                       \
    __builtin_amdgcn_s_setprio(1);                                           \
    MMAP(1);                                                                 \
    __builtin_amdgcn_s_setprio(0);                                           \
    __builtin_amdgcn_s_barrier();                                            \
    /* P3: bf(2); stage B(kt+2)s01 -> buf; MFMA nf=2 */                      \
    LDB(CUR, 2);                                                             \
    if (S2) STAGE_B01(CUR, qB01);                                            \
    __builtin_amdgcn_s_barrier();                                            \
    asm volatile("s_waitcnt lgkmcnt(0)" ::: "memory");                       \
    __builtin_amdgcn_s_setprio(1);                                           \
    MMAP(2);                                                                 \
    __builtin_amdgcn_s_setprio(0);                                           \
    __builtin_amdgcn_s_barrier();                                            \
    /* P4: bf(3); MFMA nf=3; counted vmcnt */                                \
    LDB(CUR, 3);                                                             \
    __builtin_amdgcn_s_barrier();                                            \
    asm volatile("s_waitcnt lgkmcnt(0)" ::: "memory");                       \
    __builtin_amdgcn_s_setprio(1);                                           \
    MMAP(3);                                                                 \
    __builtin_amdgcn_s_setprio(0);                                           \
    asm volatile("s_waitcnt vmcnt(" #VN ")" ::: "memory");                   \
    __builtin_amdgcn_s_barrier();                                            \
    qA += 64; qB01 += 64; qB23 += 64; }

    // ---- prologue: tile0 full -> buf0; tile1 {A, Bs01} -> buf1 ----
    STAGE_A(0, pAst); STAGE_B01(0, pB01); STAGE_B23(0, pB23);
    STAGE_A(1, pAst + 64); STAGE_B01(1, pB01 + 64);
    asm volatile("s_waitcnt vmcnt(3)" ::: "memory");   // tile0's 4 landed
    __builtin_amdgcn_s_barrier();

    const _Float16* qA   = pAst + 128;   // A(kt+2) source (k = (kt+2)*64)
    const _Float16* qB01 = pB01 + 128;   // B(kt+2) s01
    const _Float16* qB23 = pB23 + 64;    // B(kt+1) s23

    for (int kt = 0; kt < 100; kt += 2) {
        ROUND(0, 1, 1, 3);
        ROUND(1, 1, 1, 3);
    }
    ROUND(0, 1, 0, 0);   // kt=100: stage B(101)s23 only; drain all
    ROUND(1, 0, 0, 0);   // kt=101: compute only

    // ---- epilogue: C/D layout col=lane&15, row=(lane>>4)*4+reg ----
    #pragma unroll
    for (int nf = 0; nf < 4; ++nf) {
        const long col = tile_n + wn * 64 + nf * 16 + fr;
        if (col < KP) {
            const bool val = col < GN;
            const float bv = val ? bias[col] : 0.f;
            #pragma unroll
            for (int mi = 0; mi < 4; ++mi) {
                const long row = tile_m + wm * 64 + mi * 16 + fp * 4;
                #pragma unroll
                for (int r = 0; r < 4; ++r) {
                    float v = acc[mi][nf][r] + bv;
                    v = v > 0.f ? v : 0.f;
                    // pad cols [6432,6528) get 0 (K-pad of next GEMM's A)
                    C[(row + r) * (long)KP + col] = val ? (_Float16)v : (_Float16)0.f;
                }
            }
        }
    }

#undef GLD
#undef STAGE_A
#undef STAGE_B01
#undef STAGE_B23
#undef LDAALL
#undef LDB
#undef MMAP
#undef ROUND
}

// ---------------------------------------------------------------------------
// Final projection: out[b,o] = sum_k F[b,k]*wo[o,k] + bo[o].
// ---------------------------------------------------------------------------
__global__ __launch_bounds__(256) void final_out(
    const _Float16* __restrict__ F, const float* __restrict__ wo,
    const float* __restrict__ bo, float* __restrict__ out)
{
    __shared__ float red[4][8];
    const long b   = blockIdx.x;
    const int tid  = threadIdx.x;
    const int lane = tid & 63;
    const int wave = tid >> 6;
    float acc[5] = {0.f, 0.f, 0.f, 0.f, 0.f};
    const _Float16* f = F + b * KP;

    const int c1 = (wave + 1) * 402;
    for (int c = wave * 402 + lane; c < c1; c += 64) {
        const int k = c << 2;
        v4h f4 = *(const v4h*)(f + k);
        const float f0 = (float)f4[0], f1 = (float)f4[1];
        const float f2 = (float)f4[2], f3 = (float)f4[3];
        #pragma unroll
        for (int o = 0; o < 5; ++o) {
            const float4 w4 = *(const float4*)(wo + o * GK + k);
            acc[o] += f0 * w4.x + f1 * w4.y + f2 * w4.z + f3 * w4.w;
        }
    }
    #pragma unroll
    for (int o = 0; o < 5; ++o) {
        #pragma unroll
        for (int off = 32; off > 0; off >>= 1) acc[o] += __shfl_down(acc[o], off, 64);
    }
    if (lane == 0) {
        #pragma unroll
        for (int o = 0; o < 5; ++o) red[wave][o] = acc[o];
    }
    __syncthreads();
    if (tid < 5)
        out[b * 5 + tid] = red[0][tid] + red[1][tid] + red[2][tid] + red[3][tid] + bo[tid];
}

// ---------------------------------------------------------------------------
extern "C" void kernel_launch(void* const* d_in, const int* in_sizes, int n_in,
                              void* d_out, int out_size, void* d_ws, size_t ws_size,
                              hipStream_t stream)
{
    const float* x  = (const float*)d_in[0];
    const float* w1 = (const float*)d_in[1];
    const float* b1 = (const float*)d_in[2];
    const float* w2 = (const float*)d_in[3];
    const float* b2 = (const float*)d_in[4];
    const float* wl = (const float*)d_in[5];
    const float* bl = (const float*)d_in[6];
    const float* wo = (const float*)d_in[7];
    const float* bo = (const float*)d_in[8];
    float* out = (float*)d_out;

    char* ws = (char*)d_ws;
    _Float16* Wh = (_Float16*)ws;                                   // 6432*6528*2 = 83,976,192 B
    _Float16* F0 = (_Float16*)(ws + 83976192);                      // 2048*6528*2 = 26,738,688 B
    _Float16* F1 = (_Float16*)(ws + 83976192 + 26738688);

    convert_w<<<dim3(7, GN), 256, 0, stream>>>(wl, Wh);
    conv_feat<<<GM, 256, 0, stream>>>(x, w1, b1, w2, b2, F0);
    gemm16<<<208, 1024, 0, stream>>>(F0, Wh, bl, F1);
    gemm16<<<208, 1024, 0, stream>>>(F1, Wh, bl, F0);
    gemm16<<<208, 1024, 0, stream>>>(F0, Wh, bl, F1);
    gemm16<<<208, 1024, 0, stream>>>(F1, Wh, bl, F0);
    final_out<<<GM, 256, 0, stream>>>(F0, wo, bo, out);
}